// Round 18
// baseline (182.702 us; speedup 1.0000x reference)
//
#include <hip/hip_runtime.h>

#define NN 50000
#define NE 400000

typedef __attribute__((ext_vector_type(8))) short short8v;
typedef __attribute__((ext_vector_type(4))) float f32x4;

__device__ __forceinline__ unsigned short f2bf_rtn(float x) {
    unsigned u = __float_as_uint(x);
    unsigned r = u + 0x7FFFu + ((u >> 16) & 1u);
    return (unsigned short)(r >> 16);
}
__device__ __forceinline__ float bf2f(unsigned short h) {
    return __uint_as_float(((unsigned)h) << 16);
}

// ---------------- prep: x->packed bf16, zero counts+cursor, convert weights (hi only) ----------------
__global__ void prep_kernel(const float* __restrict__ x,
                            const float* __restrict__ W1, const float* __restrict__ W2,
                            const float* __restrict__ Wmu, const float* __restrict__ Wls,
                            unsigned* __restrict__ xp, int* __restrict__ zero_base,
                            unsigned short* __restrict__ w1t_hi,
                            unsigned short* __restrict__ w2t_hi,
                            unsigned short* __restrict__ wct_hi) {
    int b = blockIdx.x, tid = threadIdx.x;
    if (b < 12500) {
        int idx = b * 256 + tid;  // < 3,200,000
        int i = idx >> 6, c2 = (idx & 63) * 2;
        long xb = (long)i * 109;
        float v0 = (c2 < 109) ? x[xb + c2] : 0.0f;
        float v1 = (c2 + 1 < 109) ? x[xb + c2 + 1] : 0.0f;
        xp[idx] = (unsigned)f2bf_rtn(v0) | ((unsigned)f2bf_rtn(v1) << 16);
    } else if (b < 12891) {
        int i = (b - 12500) * 256 + tid;
        if (i < 100096) zero_base[i] = 0;
    } else if (b < 13051) {
        int idx = (b - 12891) * 256 + tid;  // < 40960
        int n = idx >> 7, k = idx & 127;
        float v = (k < 109) ? W1[(long)k * 320 + n] : 0.0f;
        w1t_hi[idx] = f2bf_rtn(v);
    } else if (b < 13131) {
        int idx = (b - 13051) * 256 + tid;  // < 20480
        int n = idx / 320, k = idx - n * 320;
        w2t_hi[idx] = f2bf_rtn(W2[(long)k * 64 + n]);
    } else {
        int idx = (b - 13131) * 256 + tid;  // < 4096
        int n = idx >> 6, k = idx & 63;
        float v = (n < 32) ? Wmu[k * 32 + n] : Wls[k * 32 + (n - 32)];
        wct_hi[idx] = f2bf_rtn(v);
    }
}

__global__ void hist_kernel(const int* __restrict__ dst, int* __restrict__ counts) {
    for (int e = blockIdx.x * blockDim.x + threadIdx.x; e < NE; e += gridDim.x * blockDim.x)
        atomicAdd(&counts[dst[e]], 1);
}

// dinv + block-local exclusive scan (bsum = per-block total)
__global__ void dinv_scan1_kernel(const int* __restrict__ counts, float* __restrict__ dinv,
                                  int* __restrict__ rowstart, int* __restrict__ bsum) {
    __shared__ int tmp[256];
    int tid = threadIdx.x;
    int i = blockIdx.x * 256 + tid;
    int v = (i < NN) ? counts[i] : 0;
    if (i < NN) dinv[i] = rsqrtf((float)(v + 1));  // +1 self loop
    tmp[tid] = v;
    __syncthreads();
    for (int off = 1; off < 256; off <<= 1) {
        int t = 0;
        if (tid >= off) t = tmp[tid - off];
        __syncthreads();
        if (tid >= off) tmp[tid] += t;
        __syncthreads();
    }
    if (i < NN) rowstart[i] = tmp[tid] - v;  // exclusive within block
    if (tid == 255) bsum[blockIdx.x] = tmp[255];
}

// fused scan2+scan3
__global__ void scan23_kernel(int* __restrict__ rowstart, const int* __restrict__ bsum) {
    __shared__ int red[4];
    int tid = threadIdx.x;
    int v = (tid < 196 && tid < (int)blockIdx.x) ? bsum[tid] : 0;
    for (int off = 32; off > 0; off >>= 1) v += __shfl_down(v, off, 64);
    if ((tid & 63) == 0) red[tid >> 6] = v;
    __syncthreads();
    int pref = red[0] + red[1] + red[2] + red[3];
    int i = blockIdx.x * 256 + tid;
    if (i < NN) rowstart[i] += pref;
    if (i == 0) rowstart[NN] = NE;
}

__global__ void scatter_kernel(const int* __restrict__ src, const int* __restrict__ dst,
                               const int* __restrict__ rowstart, int* __restrict__ cursor,
                               int* __restrict__ esrc) {
    for (int e = blockIdx.x * blockDim.x + threadIdx.x; e < NE; e += gridDim.x * blockDim.x) {
        int d = dst[e];
        int pos = rowstart[d] + atomicAdd(&cursor[d], 1);
        esrc[pos] = src[e];
    }
}

// ---------------- FUSED layer 1 + 2a: agg(x) -> LDS; h1 = relu(@W1+b1) -> LDS; g2b = (@W2)*dinv ----------------
// 1024 threads = 16 waves; block = 64 nodes. Wave w aggregates nodes m0+w*4..+3 (packed-bf16
// gather identical to old agg109). Phase A/B MFMA accumulation order identical to old gemm12.
#define LDA_T 136  // As/Bs row stride (u16); 272 B
#define LDH 328    // Hs row stride (u16)

__global__ __launch_bounds__(1024) void agg_gemm12_kernel(const int* __restrict__ rowstart,
                                                          const int* __restrict__ esrc,
                                                          const float* __restrict__ dinv,
                                                          const unsigned* __restrict__ xp,
                                                          const unsigned short* __restrict__ w1t,
                                                          const unsigned short* __restrict__ w2t,
                                                          const float* __restrict__ b1,
                                                          unsigned short* __restrict__ g2b) {
    __shared__ unsigned short As[64 * LDA_T];  // xa tile [64][128] bf16
    __shared__ unsigned short Bs[64 * LDA_T];  // weight chunk
    __shared__ unsigned short Hs[64 * LDH];    // h1 tile [64][320] bf16
    int tid = threadIdx.x;
    int wid = tid >> 6, lane = tid & 63;
    int l15 = lane & 15, l4 = lane >> 4;

    // bijective XCD swizzle
    int T = gridDim.x;
    int xcd = blockIdx.x & 7, jj = blockIdx.x >> 3;
    int q = T >> 3, r0 = T & 7;
    int start = (xcd < r0) ? xcd * (q + 1) : r0 * (q + 1) + (xcd - r0) * q;
    int m0 = (start + jj) * 64;

    // stage Bs = W1T chunk 0 (64 outcols x 128 K): 1024 uint4, one per thread
    {
        int row = tid >> 4, slot = tid & 15;
        *(uint4*)&Bs[row * LDA_T + slot * 8] = *(const uint4*)&w1t[(long)row * 128 + slot * 8];
    }

    // aggregation (identical math to old agg109): wave wid -> 4 nodes; lane = channels 2l,2l+1
    #pragma unroll
    for (int t = 0; t < 4; ++t) {
        int node = m0 + wid * 4 + t;
        int i = node < NN ? node : NN - 1;  // clamp; stores guarded later
        float wd = dinv[i];
        unsigned pself = xp[(long)i * 64 + lane];
        float acc0 = __uint_as_float(pself << 16) * wd;
        float acc1 = __uint_as_float(pself & 0xFFFF0000u) * wd;
        int j0 = rowstart[i], j1 = rowstart[i + 1];
        int j = j0;
        for (; j + 8 <= j1; j += 8) {
            int s[8];
            float w[8];
            unsigned pp[8];
            #pragma unroll
            for (int u = 0; u < 8; ++u) s[u] = esrc[j + u];
            #pragma unroll
            for (int u = 0; u < 8; ++u) w[u] = dinv[s[u]];
            #pragma unroll
            for (int u = 0; u < 8; ++u) pp[u] = xp[(long)s[u] * 64 + lane];
            #pragma unroll
            for (int u = 0; u < 8; ++u) {
                acc0 = fmaf(__uint_as_float(pp[u] << 16), w[u], acc0);
                acc1 = fmaf(__uint_as_float(pp[u] & 0xFFFF0000u), w[u], acc1);
            }
        }
        for (; j + 4 <= j1; j += 4) {
            int s0 = esrc[j], s1 = esrc[j + 1], s2 = esrc[j + 2], s3 = esrc[j + 3];
            float w0 = dinv[s0], w1 = dinv[s1], w2 = dinv[s2], w3 = dinv[s3];
            unsigned p0 = xp[(long)s0 * 64 + lane], p1 = xp[(long)s1 * 64 + lane];
            unsigned p2 = xp[(long)s2 * 64 + lane], p3 = xp[(long)s3 * 64 + lane];
            acc0 = fmaf(__uint_as_float(p0 << 16), w0, acc0);
            acc1 = fmaf(__uint_as_float(p0 & 0xFFFF0000u), w0, acc1);
            acc0 = fmaf(__uint_as_float(p1 << 16), w1, acc0);
            acc1 = fmaf(__uint_as_float(p1 & 0xFFFF0000u), w1, acc1);
            acc0 = fmaf(__uint_as_float(p2 << 16), w2, acc0);
            acc1 = fmaf(__uint_as_float(p2 & 0xFFFF0000u), w2, acc1);
            acc0 = fmaf(__uint_as_float(p3 << 16), w3, acc0);
            acc1 = fmaf(__uint_as_float(p3 & 0xFFFF0000u), w3, acc1);
        }
        for (; j < j1; ++j) {
            int s = esrc[j];
            float w = dinv[s];
            unsigned pv = xp[(long)s * 64 + lane];
            acc0 = fmaf(__uint_as_float(pv << 16), w, acc0);
            acc1 = fmaf(__uint_as_float(pv & 0xFFFF0000u), w, acc1);
        }
        acc0 *= wd;
        acc1 *= wd;
        unsigned val = (unsigned)f2bf_rtn(acc0) | ((unsigned)f2bf_rtn(acc1) << 16);
        *(unsigned*)&As[(wid * 4 + t) * LDA_T + lane * 2] = val;
    }
    __syncthreads();

    // ---- phase A: Hs = relu(As @ W1 + b1); wave = fragment (r,c), 5 col-chunks ----
    int r = wid >> 2, c = wid & 3;
    for (int nc = 0; nc < 5; ++nc) {
        f32x4 acc = {};
        #pragma unroll
        for (int ks = 0; ks < 4; ++ks) {
            int koff = ks * 32 + l4 * 8;
            short8v ah = *(const short8v*)&As[(r * 16 + l15) * LDA_T + koff];
            short8v bh = *(const short8v*)&Bs[(c * 16 + l15) * LDA_T + koff];
            acc = __builtin_amdgcn_mfma_f32_16x16x32_bf16(ah, bh, acc, 0, 0, 0);
        }
        int gcol = nc * 64 + c * 16 + l15;
        float bb = b1[gcol];
        int rb = r * 16 + l4 * 4;
        #pragma unroll
        for (int q2 = 0; q2 < 4; ++q2) {
            float v = acc[q2] + bb;
            v = v > 0.0f ? v : 0.0f;
            Hs[(rb + q2) * LDH + gcol] = f2bf_rtn(v);
        }
        __syncthreads();
        if (nc < 4) {
            int row = tid >> 4, slot = tid & 15;
            *(uint4*)&Bs[row * LDA_T + slot * 8] =
                *(const uint4*)&w1t[(long)(nc * 64 + 64 + row) * 128 + slot * 8];
            __syncthreads();
        }
    }

    // ---- phase B: g2b = (Hs @ W2) * dinv[row]; wave = fragment (r,c), K=320 ----
    f32x4 acc2 = {};
    for (int kc = 0; kc < 5; ++kc) {
        if (tid < 512) {
            int row = tid >> 3, slot = tid & 7;
            *(uint4*)&Bs[row * LDA_T + slot * 8] =
                *(const uint4*)&w2t[(long)row * 320 + kc * 64 + slot * 8];
        }
        __syncthreads();
        #pragma unroll
        for (int ks = 0; ks < 2; ++ks) {
            int koff = ks * 32 + l4 * 8;
            short8v ah = *(const short8v*)&Hs[(r * 16 + l15) * LDH + kc * 64 + koff];
            short8v bh = *(const short8v*)&Bs[(c * 16 + l15) * LDA_T + koff];
            acc2 = __builtin_amdgcn_mfma_f32_16x16x32_bf16(ah, bh, acc2, 0, 0, 0);
        }
        __syncthreads();
    }
    int rbase = m0 + r * 16 + l4 * 4;
    int gcol2 = c * 16 + l15;
    #pragma unroll
    for (int q2 = 0; q2 < 4; ++q2) {
        int grow = rbase + q2;
        if (grow >= NN) continue;
        g2b[(long)grow * 64 + gcol2] = f2bf_rtn(acc2[q2] * dinv[grow]);
    }
}

// C = 64, layer 2 epilogue: relu(v + b) on bf16 gather -> bf16 HI only; MLP depth 8/4
__global__ __launch_bounds__(256) void agg64_relu_bf16_kernel(const int* __restrict__ rowstart,
                                                              const int* __restrict__ esrc,
                                                              const float* __restrict__ dinv,
                                                              const unsigned short* __restrict__ g,
                                                              const float* __restrict__ b,
                                                              unsigned short* __restrict__ hhi) {
    int wave = blockIdx.x * (blockDim.x >> 6) + (threadIdx.x >> 6);
    if (wave >= NN) return;
    int lane = threadIdx.x & 63;
    long base = (long)wave * 64;
    float acc = bf2f(g[base + lane]);
    int j0 = rowstart[wave], j1 = rowstart[wave + 1];
    int j = j0;
    for (; j + 8 <= j1; j += 8) {
        int s[8];
        float pp[8];
        #pragma unroll
        for (int u = 0; u < 8; ++u) s[u] = esrc[j + u];
        #pragma unroll
        for (int u = 0; u < 8; ++u) pp[u] = bf2f(g[(long)s[u] * 64 + lane]);
        #pragma unroll
        for (int u = 0; u < 8; ++u) acc += pp[u];
    }
    for (; j + 4 <= j1; j += 4) {
        int s0 = esrc[j], s1 = esrc[j + 1], s2 = esrc[j + 2], s3 = esrc[j + 3];
        float p0 = bf2f(g[(long)s0 * 64 + lane]), p1 = bf2f(g[(long)s1 * 64 + lane]);
        float p2 = bf2f(g[(long)s2 * 64 + lane]), p3 = bf2f(g[(long)s3 * 64 + lane]);
        acc += p0 + p1 + p2 + p3;
    }
    for (; j < j1; ++j) acc += bf2f(g[(long)esrc[j] * 64 + lane]);
    float v = acc * dinv[wave] + b[lane];
    v = v > 0.0f ? v : 0.0f;
    hhi[base + lane] = f2bf_rtn(v);
}

// ---------------- FUSED layers 3+4: aggregate h2 into LDS tile, then 64x64x64 MFMA -> out ----------------
#define LDT 72
__global__ __launch_bounds__(1024) void agg_gemm3_kernel(const int* __restrict__ rowstart,
                                                         const int* __restrict__ esrc,
                                                         const float* __restrict__ dinv,
                                                         const unsigned short* __restrict__ h,
                                                         const unsigned short* __restrict__ wct_hi,
                                                         const float* __restrict__ bmu,
                                                         const float* __restrict__ bls,
                                                         float* __restrict__ out) {
    __shared__ unsigned short As[64 * LDT];
    __shared__ unsigned short Bs[64 * LDT];
    int tid = threadIdx.x;
    int wid = tid >> 6, lane = tid & 63;
    int m0 = blockIdx.x * 64;

    // stage B = wct (64x64 bf16) early
    if (tid < 512) {
        int row = tid >> 3, slot = tid & 7;
        *(uint4*)&Bs[row * LDT + slot * 8] = *(const uint4*)&wct_hi[row * 64 + slot * 8];
    }

    // aggregation: wave wid handles 4 nodes
    #pragma unroll
    for (int t = 0; t < 4; ++t) {
        int node = m0 + wid * 4 + t;
        int i = node < NN ? node : NN - 1;  // clamp; epilogue guards stores
        long base = (long)i * 64;
        float wd = dinv[i];
        float acc = bf2f(h[base + lane]) * wd;
        int j0 = rowstart[i], j1 = rowstart[i + 1];
        int j = j0;
        for (; j + 8 <= j1; j += 8) {
            int s[8];
            float w[8], pp[8];
            #pragma unroll
            for (int u = 0; u < 8; ++u) s[u] = esrc[j + u];
            #pragma unroll
            for (int u = 0; u < 8; ++u) w[u] = dinv[s[u]];
            #pragma unroll
            for (int u = 0; u < 8; ++u) pp[u] = bf2f(h[(long)s[u] * 64 + lane]);
            #pragma unroll
            for (int u = 0; u < 8; ++u) acc = fmaf(pp[u], w[u], acc);
        }
        for (; j + 4 <= j1; j += 4) {
            int s0 = esrc[j], s1 = esrc[j + 1], s2 = esrc[j + 2], s3 = esrc[j + 3];
            float w0 = dinv[s0], w1 = dinv[s1], w2 = dinv[s2], w3 = dinv[s3];
            float p0 = bf2f(h[(long)s0 * 64 + lane]), p1 = bf2f(h[(long)s1 * 64 + lane]);
            float p2 = bf2f(h[(long)s2 * 64 + lane]), p3 = bf2f(h[(long)s3 * 64 + lane]);
            acc = fmaf(p0, w0, acc); acc = fmaf(p1, w1, acc);
            acc = fmaf(p2, w2, acc); acc = fmaf(p3, w3, acc);
        }
        for (; j < j1; ++j) {
            int s = esrc[j];
            acc = fmaf(bf2f(h[(long)s * 64 + lane]), dinv[s], acc);
        }
        As[(wid * 4 + t) * LDT + lane] = f2bf_rtn(acc * wd);
    }
    __syncthreads();

    // MFMA: wave wid -> (r=wid>>2, c=wid&3), K=64
    int r = wid >> 2, c = wid & 3;
    int l15 = lane & 15, l4 = lane >> 4;
    f32x4 acc4 = {};
    #pragma unroll
    for (int ks = 0; ks < 2; ++ks) {
        int koff = ks * 32 + l4 * 8;
        short8v ah = *(const short8v*)&As[(r * 16 + l15) * LDT + koff];
        short8v bh = *(const short8v*)&Bs[(c * 16 + l15) * LDT + koff];
        acc4 = __builtin_amdgcn_mfma_f32_16x16x32_bf16(ah, bh, acc4, 0, 0, 0);
    }
    int rbase = m0 + r * 16 + l4 * 4;
    int gcol = c * 16 + l15;
    #pragma unroll
    for (int q2 = 0; q2 < 4; ++q2) {
        int grow = rbase + q2;
        if (grow >= NN) continue;
        float v = acc4[q2];
        if (gcol < 32)
            out[(long)grow * 32 + gcol] = v + bmu[gcol];
        else
            out[(long)NN * 32 + (long)grow * 32 + (gcol - 32)] = v + bls[gcol - 32];
    }
}

extern "C" void kernel_launch(void* const* d_in, const int* in_sizes, int n_in,
                              void* d_out, int out_size, void* d_ws, size_t ws_size,
                              hipStream_t stream) {
    const float* x   = (const float*)d_in[0];
    const int*   ei  = (const int*)d_in[1];
    const int*   src = ei;       // edge_index[0]
    const int*   dst = ei + NE;  // edge_index[1]
    const float* W1  = (const float*)d_in[2];
    const float* b1  = (const float*)d_in[3];
    const float* W2  = (const float*)d_in[4];
    const float* b2  = (const float*)d_in[5];
    const float* Wmu = (const float*)d_in[6];
    const float* bmu = (const float*)d_in[7];
    const float* Wls = (const float*)d_in[8];
    const float* bls = (const float*)d_in[9];
    float* out = (float*)d_out;

    // ---- workspace layout ----
    char* p = (char*)d_ws;
    float* dinv   = (float*)p; p += 50048 * 4;
    int* counts   = (int*)p;   p += 50048 * 4;  // counts+cursor zeroed together in prep
    int* cursor   = (int*)p;   p += 50048 * 4;
    int* rowstart = (int*)p;   p += 50056 * 4;
    int* bsum     = (int*)p;   p += 256 * 4;
    int* esrc     = (int*)p;   p += 400000 * 4;
    unsigned* xp          = (unsigned*)p;       p += 50000L * 64 * 4;   // packed bf16 x
    unsigned short* g2b   = (unsigned short*)p; p += 50000L * 64 * 2;
    unsigned short* h2_hi = (unsigned short*)p; p += 50000L * 64 * 2;
    unsigned short* w1t_hi = (unsigned short*)p; p += 320 * 128 * 2;
    unsigned short* w2t_hi = (unsigned short*)p; p += 64 * 320 * 2;
    unsigned short* wct_hi = (unsigned short*)p; p += 64 * 64 * 2;

    const int TB = 256;
    const int NB_NODES = (NN + TB - 1) / TB;     // 196
    const int NB_AGG = (NN * 64 + TB - 1) / TB;  // 12500 (wave per node)

    // ---- prep + CSR build ----
    prep_kernel<<<13147, TB, 0, stream>>>(x, W1, W2, Wmu, Wls, xp, counts,
                                          w1t_hi, w2t_hi, wct_hi);
    hist_kernel<<<1024, TB, 0, stream>>>(dst, counts);
    dinv_scan1_kernel<<<NB_NODES, TB, 0, stream>>>(counts, dinv, rowstart, bsum);
    scan23_kernel<<<NB_NODES, TB, 0, stream>>>(rowstart, bsum);
    scatter_kernel<<<1024, TB, 0, stream>>>(src, dst, rowstart, cursor, esrc);

    // ---- FUSED layer1 agg + GEMM1 + GEMM2: g2b = (relu(agg(x)@W1+b1)@W2)*dinv ----
    agg_gemm12_kernel<<<782, 1024, 0, stream>>>(rowstart, esrc, dinv, xp,
                                                w1t_hi, w2t_hi, b1, g2b);

    // ---- layer 2 agg: h2 = relu(agg(g2b) + b2) -> bf16 hi ----
    agg64_relu_bf16_kernel<<<NB_AGG, TB, 0, stream>>>(rowstart, esrc, dinv, g2b, b2, h2_hi);

    // ---- layers 3+4 FUSED: aggregate h2 + 64x64x64 GEMM -> out ----
    agg_gemm3_kernel<<<782, 1024, 0, stream>>>(rowstart, esrc, dinv, h2_hi, wct_hi,
                                               bmu, bls, out);
}

// Round 19
// 158.678 us; speedup vs baseline: 1.1514x; 1.1514x over previous
//
#include <hip/hip_runtime.h>

#define NN 50000
#define NE 400000

typedef __attribute__((ext_vector_type(8))) short short8v;
typedef __attribute__((ext_vector_type(4))) float f32x4;

__device__ __forceinline__ unsigned short f2bf_rtn(float x) {
    unsigned u = __float_as_uint(x);
    unsigned r = u + 0x7FFFu + ((u >> 16) & 1u);
    return (unsigned short)(r >> 16);
}
__device__ __forceinline__ float bf2f(unsigned short h) {
    return __uint_as_float(((unsigned)h) << 16);
}

// ---------------- prep: x->packed bf16, zero counts+cursor, convert weights (hi only) ----------------
__global__ void prep_kernel(const float* __restrict__ x,
                            const float* __restrict__ W1, const float* __restrict__ W2,
                            const float* __restrict__ Wmu, const float* __restrict__ Wls,
                            unsigned* __restrict__ xp, int* __restrict__ zero_base,
                            unsigned short* __restrict__ w1t_hi,
                            unsigned short* __restrict__ w2t_hi,
                            unsigned short* __restrict__ wct_hi) {
    int b = blockIdx.x, tid = threadIdx.x;
    if (b < 12500) {
        int idx = b * 256 + tid;  // < 3,200,000
        int i = idx >> 6, c2 = (idx & 63) * 2;
        long xb = (long)i * 109;
        float v0 = (c2 < 109) ? x[xb + c2] : 0.0f;
        float v1 = (c2 + 1 < 109) ? x[xb + c2 + 1] : 0.0f;
        xp[idx] = (unsigned)f2bf_rtn(v0) | ((unsigned)f2bf_rtn(v1) << 16);
    } else if (b < 12891) {
        int i = (b - 12500) * 256 + tid;
        if (i < 100096) zero_base[i] = 0;
    } else if (b < 13051) {
        int idx = (b - 12891) * 256 + tid;  // < 40960
        int n = idx >> 7, k = idx & 127;
        float v = (k < 109) ? W1[(long)k * 320 + n] : 0.0f;
        w1t_hi[idx] = f2bf_rtn(v);
    } else if (b < 13131) {
        int idx = (b - 13051) * 256 + tid;  // < 20480
        int n = idx / 320, k = idx - n * 320;
        w2t_hi[idx] = f2bf_rtn(W2[(long)k * 64 + n]);
    } else {
        int idx = (b - 13131) * 256 + tid;  // < 4096
        int n = idx >> 6, k = idx & 63;
        float v = (n < 32) ? Wmu[k * 32 + n] : Wls[k * 32 + (n - 32)];
        wct_hi[idx] = f2bf_rtn(v);
    }
}

__global__ void hist_kernel(const int* __restrict__ dst, int* __restrict__ counts) {
    for (int e = blockIdx.x * blockDim.x + threadIdx.x; e < NE; e += gridDim.x * blockDim.x)
        atomicAdd(&counts[dst[e]], 1);
}

// dinv + block-local exclusive scan (bsum = per-block total)
__global__ void dinv_scan1_kernel(const int* __restrict__ counts, float* __restrict__ dinv,
                                  int* __restrict__ rowstart, int* __restrict__ bsum) {
    __shared__ int tmp[256];
    int tid = threadIdx.x;
    int i = blockIdx.x * 256 + tid;
    int v = (i < NN) ? counts[i] : 0;
    if (i < NN) dinv[i] = rsqrtf((float)(v + 1));  // +1 self loop
    tmp[tid] = v;
    __syncthreads();
    for (int off = 1; off < 256; off <<= 1) {
        int t = 0;
        if (tid >= off) t = tmp[tid - off];
        __syncthreads();
        if (tid >= off) tmp[tid] += t;
        __syncthreads();
    }
    if (i < NN) rowstart[i] = tmp[tid] - v;  // exclusive within block
    if (tid == 255) bsum[blockIdx.x] = tmp[255];
}

// fused scan2+scan3
__global__ void scan23_kernel(int* __restrict__ rowstart, const int* __restrict__ bsum) {
    __shared__ int red[4];
    int tid = threadIdx.x;
    int v = (tid < 196 && tid < (int)blockIdx.x) ? bsum[tid] : 0;
    for (int off = 32; off > 0; off >>= 1) v += __shfl_down(v, off, 64);
    if ((tid & 63) == 0) red[tid >> 6] = v;
    __syncthreads();
    int pref = red[0] + red[1] + red[2] + red[3];
    int i = blockIdx.x * 256 + tid;
    if (i < NN) rowstart[i] += pref;
    if (i == 0) rowstart[NN] = NE;
}

__global__ void scatter_kernel(const int* __restrict__ src, const int* __restrict__ dst,
                               const int* __restrict__ rowstart, int* __restrict__ cursor,
                               int* __restrict__ esrc) {
    for (int e = blockIdx.x * blockDim.x + threadIdx.x; e < NE; e += gridDim.x * blockDim.x) {
        int d = dst[e];
        int pos = rowstart[d] + atomicAdd(&cursor[d], 1);
        esrc[pos] = src[e];
    }
}

// ---------------- CSR aggregation, layer 1: packed-bf16 gather -> bf16 HI out ----------------
__global__ __launch_bounds__(256) void agg109_packed_kernel(const int* __restrict__ rowstart,
                                                            const int* __restrict__ esrc,
                                                            const float* __restrict__ dinv,
                                                            const unsigned* __restrict__ xp,
                                                            unsigned* __restrict__ xa_hi32) {
    int wave = blockIdx.x * (blockDim.x >> 6) + (threadIdx.x >> 6);
    if (wave >= NN) return;
    int lane = threadIdx.x & 63;
    float wd = dinv[wave];
    unsigned pself = xp[(long)wave * 64 + lane];
    float acc0 = __uint_as_float(pself << 16) * wd;
    float acc1 = __uint_as_float(pself & 0xFFFF0000u) * wd;
    int j0 = rowstart[wave], j1 = rowstart[wave + 1];
    int j = j0;
    for (; j + 8 <= j1; j += 8) {
        int s[8];
        float w[8];
        unsigned pp[8];
        #pragma unroll
        for (int u = 0; u < 8; ++u) s[u] = esrc[j + u];
        #pragma unroll
        for (int u = 0; u < 8; ++u) w[u] = dinv[s[u]];
        #pragma unroll
        for (int u = 0; u < 8; ++u) pp[u] = xp[(long)s[u] * 64 + lane];
        #pragma unroll
        for (int u = 0; u < 8; ++u) {
            acc0 = fmaf(__uint_as_float(pp[u] << 16), w[u], acc0);
            acc1 = fmaf(__uint_as_float(pp[u] & 0xFFFF0000u), w[u], acc1);
        }
    }
    for (; j + 4 <= j1; j += 4) {
        int s0 = esrc[j], s1 = esrc[j + 1], s2 = esrc[j + 2], s3 = esrc[j + 3];
        float w0 = dinv[s0], w1 = dinv[s1], w2 = dinv[s2], w3 = dinv[s3];
        unsigned p0 = xp[(long)s0 * 64 + lane], p1 = xp[(long)s1 * 64 + lane];
        unsigned p2 = xp[(long)s2 * 64 + lane], p3 = xp[(long)s3 * 64 + lane];
        acc0 = fmaf(__uint_as_float(p0 << 16), w0, acc0);
        acc1 = fmaf(__uint_as_float(p0 & 0xFFFF0000u), w0, acc1);
        acc0 = fmaf(__uint_as_float(p1 << 16), w1, acc0);
        acc1 = fmaf(__uint_as_float(p1 & 0xFFFF0000u), w1, acc1);
        acc0 = fmaf(__uint_as_float(p2 << 16), w2, acc0);
        acc1 = fmaf(__uint_as_float(p2 & 0xFFFF0000u), w2, acc1);
        acc0 = fmaf(__uint_as_float(p3 << 16), w3, acc0);
        acc1 = fmaf(__uint_as_float(p3 & 0xFFFF0000u), w3, acc1);
    }
    for (; j < j1; ++j) {
        int s = esrc[j];
        float w = dinv[s];
        unsigned pv = xp[(long)s * 64 + lane];
        acc0 = fmaf(__uint_as_float(pv << 16), w, acc0);
        acc1 = fmaf(__uint_as_float(pv & 0xFFFF0000u), w, acc1);
    }
    acc0 *= wd;
    acc1 *= wd;
    xa_hi32[(long)wave * 64 + lane] =
        (unsigned)f2bf_rtn(acc0) | ((unsigned)f2bf_rtn(acc1) << 16);
}

// ---------------- FUSED layers 1b+2a: h1 = relu(xa@W1+b1) in LDS; g2b = (h1@W2)*dinv ----------------
// 256 threads = 4 waves; block = 64 rows. Phase A: 5 chunks of 64 cols (K=128).
// Phase B: K=320 in 5 chunks. h1 never touches HBM.
#define LDA_T 136  // As/Bs row stride (u16); 272 B -> 2-way bank aliasing (free)
#define LDH 328    // Hs row stride (u16); 656 B -> 2-way

__global__ __launch_bounds__(256) void gemm12_kernel(const unsigned short* __restrict__ xa,
                                                     const unsigned short* __restrict__ w1t,
                                                     const unsigned short* __restrict__ w2t,
                                                     const float* __restrict__ b1,
                                                     const float* __restrict__ dinv,
                                                     unsigned short* __restrict__ g2b) {
    __shared__ unsigned short As[64 * LDA_T];
    __shared__ unsigned short Bs[64 * LDA_T];
    __shared__ unsigned short Hs[64 * LDH];
    int tid = threadIdx.x;
    int wid = tid >> 6, lane = tid & 63;
    int l15 = lane & 15, l4 = lane >> 4;

    // bijective XCD swizzle (grid_n = 1)
    int T = gridDim.x;
    int xcd = blockIdx.x & 7, jj = blockIdx.x >> 3;
    int q = T >> 3, r = T & 7;
    int start = (xcd < r) ? xcd * (q + 1) : r * (q + 1) + (xcd - r) * q;
    int bm0 = (start + jj) * 64;

    // stage As = xa tile [64][128]
    #pragma unroll
    for (int r2 = 0; r2 < 4; ++r2) {
        int idx = tid + 256 * r2;  // < 1024
        int row = idx >> 4, slot = idx & 15;
        int grow = bm0 + row;
        if (grow >= NN) grow = NN - 1;  // clamp; stores guarded
        *(uint4*)&As[row * LDA_T + slot * 8] = *(const uint4*)&xa[(long)grow * 128 + slot * 8];
    }
    // stage Bs = W1T chunk 0 ([64 outcols][128])
    #pragma unroll
    for (int r2 = 0; r2 < 4; ++r2) {
        int idx = tid + 256 * r2;
        int row = idx >> 4, slot = idx & 15;
        *(uint4*)&Bs[row * LDA_T + slot * 8] = *(const uint4*)&w1t[(long)row * 128 + slot * 8];
    }
    __syncthreads();

    // ---- phase A: Hs = relu(As @ W1 + b1) ----
    for (int nc = 0; nc < 5; ++nc) {
        f32x4 acc[4] = {};
        #pragma unroll
        for (int ks = 0; ks < 4; ++ks) {
            int koff = ks * 32 + l4 * 8;
            short8v ah = *(const short8v*)&As[(wid * 16 + l15) * LDA_T + koff];
            #pragma unroll
            for (int n = 0; n < 4; ++n) {
                short8v bh = *(const short8v*)&Bs[(n * 16 + l15) * LDA_T + koff];
                acc[n] = __builtin_amdgcn_mfma_f32_16x16x32_bf16(ah, bh, acc[n], 0, 0, 0);
            }
        }
        int rbase = wid * 16 + l4 * 4;
        #pragma unroll
        for (int q2 = 0; q2 < 4; ++q2) {
            #pragma unroll
            for (int n = 0; n < 4; ++n) {
                int gcol = nc * 64 + n * 16 + l15;
                float v = acc[n][q2] + b1[gcol];
                v = v > 0.0f ? v : 0.0f;
                Hs[(rbase + q2) * LDH + gcol] = f2bf_rtn(v);
            }
        }
        __syncthreads();
        if (nc < 4) {
            #pragma unroll
            for (int r2 = 0; r2 < 4; ++r2) {
                int idx = tid + 256 * r2;
                int row = idx >> 4, slot = idx & 15;
                *(uint4*)&Bs[row * LDA_T + slot * 8] =
                    *(const uint4*)&w1t[(long)(nc * 64 + 64 + row) * 128 + slot * 8];
            }
            __syncthreads();
        }
    }

    // ---- phase B: g2b = (Hs @ W2) * dinv[row] ----
    f32x4 acc2[4] = {};
    for (int kc = 0; kc < 5; ++kc) {
        #pragma unroll
        for (int r2 = 0; r2 < 2; ++r2) {
            int idx = tid + 256 * r2;  // < 512
            int row = idx >> 3, slot = idx & 7;
            *(uint4*)&Bs[row * LDA_T + slot * 8] =
                *(const uint4*)&w2t[(long)row * 320 + kc * 64 + slot * 8];
        }
        __syncthreads();
        #pragma unroll
        for (int ks = 0; ks < 2; ++ks) {
            int koff = ks * 32 + l4 * 8;
            short8v ah = *(const short8v*)&Hs[(wid * 16 + l15) * LDH + kc * 64 + koff];
            #pragma unroll
            for (int n = 0; n < 4; ++n) {
                short8v bh = *(const short8v*)&Bs[(n * 16 + l15) * LDA_T + koff];
                acc2[n] = __builtin_amdgcn_mfma_f32_16x16x32_bf16(ah, bh, acc2[n], 0, 0, 0);
            }
        }
        __syncthreads();
    }
    int rbase = bm0 + wid * 16 + l4 * 4;
    #pragma unroll
    for (int q2 = 0; q2 < 4; ++q2) {
        int grow = rbase + q2;
        if (grow >= NN) continue;
        float rs = dinv[grow];
        #pragma unroll
        for (int n = 0; n < 4; ++n) {
            int gcol = n * 16 + l15;
            g2b[(long)grow * 64 + gcol] = f2bf_rtn(acc2[n][q2] * rs);
        }
    }
}

// C = 64, layer 2 epilogue: relu(v + b) on bf16 gather -> bf16 HI only; MLP depth 8/4
__global__ __launch_bounds__(256) void agg64_relu_bf16_kernel(const int* __restrict__ rowstart,
                                                              const int* __restrict__ esrc,
                                                              const float* __restrict__ dinv,
                                                              const unsigned short* __restrict__ g,
                                                              const float* __restrict__ b,
                                                              unsigned short* __restrict__ hhi) {
    int wave = blockIdx.x * (blockDim.x >> 6) + (threadIdx.x >> 6);
    if (wave >= NN) return;
    int lane = threadIdx.x & 63;
    long base = (long)wave * 64;
    float acc = bf2f(g[base + lane]);
    int j0 = rowstart[wave], j1 = rowstart[wave + 1];
    int j = j0;
    for (; j + 8 <= j1; j += 8) {
        int s[8];
        float pp[8];
        #pragma unroll
        for (int u = 0; u < 8; ++u) s[u] = esrc[j + u];
        #pragma unroll
        for (int u = 0; u < 8; ++u) pp[u] = bf2f(g[(long)s[u] * 64 + lane]);
        #pragma unroll
        for (int u = 0; u < 8; ++u) acc += pp[u];
    }
    for (; j + 4 <= j1; j += 4) {
        int s0 = esrc[j], s1 = esrc[j + 1], s2 = esrc[j + 2], s3 = esrc[j + 3];
        float p0 = bf2f(g[(long)s0 * 64 + lane]), p1 = bf2f(g[(long)s1 * 64 + lane]);
        float p2 = bf2f(g[(long)s2 * 64 + lane]), p3 = bf2f(g[(long)s3 * 64 + lane]);
        acc += p0 + p1 + p2 + p3;
    }
    for (; j < j1; ++j) acc += bf2f(g[(long)esrc[j] * 64 + lane]);
    float v = acc * dinv[wave] + b[lane];
    v = v > 0.0f ? v : 0.0f;
    hhi[base + lane] = f2bf_rtn(v);
}

// ---------------- FUSED layers 3+4: aggregate h2 into LDS tile, then 64x64x64 MFMA -> out ----------------
#define LDT 72
__global__ __launch_bounds__(1024) void agg_gemm3_kernel(const int* __restrict__ rowstart,
                                                         const int* __restrict__ esrc,
                                                         const float* __restrict__ dinv,
                                                         const unsigned short* __restrict__ h,
                                                         const unsigned short* __restrict__ wct_hi,
                                                         const float* __restrict__ bmu,
                                                         const float* __restrict__ bls,
                                                         float* __restrict__ out) {
    __shared__ unsigned short As[64 * LDT];
    __shared__ unsigned short Bs[64 * LDT];
    int tid = threadIdx.x;
    int wid = tid >> 6, lane = tid & 63;
    int m0 = blockIdx.x * 64;

    // stage B = wct (64x64 bf16) early
    if (tid < 512) {
        int row = tid >> 3, slot = tid & 7;
        *(uint4*)&Bs[row * LDT + slot * 8] = *(const uint4*)&wct_hi[row * 64 + slot * 8];
    }

    // aggregation: wave wid handles 4 nodes
    #pragma unroll
    for (int t = 0; t < 4; ++t) {
        int node = m0 + wid * 4 + t;
        int i = node < NN ? node : NN - 1;  // clamp; epilogue guards stores
        long base = (long)i * 64;
        float wd = dinv[i];
        float acc = bf2f(h[base + lane]) * wd;
        int j0 = rowstart[i], j1 = rowstart[i + 1];
        int j = j0;
        for (; j + 8 <= j1; j += 8) {
            int s[8];
            float w[8], pp[8];
            #pragma unroll
            for (int u = 0; u < 8; ++u) s[u] = esrc[j + u];
            #pragma unroll
            for (int u = 0; u < 8; ++u) w[u] = dinv[s[u]];
            #pragma unroll
            for (int u = 0; u < 8; ++u) pp[u] = bf2f(h[(long)s[u] * 64 + lane]);
            #pragma unroll
            for (int u = 0; u < 8; ++u) acc = fmaf(pp[u], w[u], acc);
        }
        for (; j + 4 <= j1; j += 4) {
            int s0 = esrc[j], s1 = esrc[j + 1], s2 = esrc[j + 2], s3 = esrc[j + 3];
            float w0 = dinv[s0], w1 = dinv[s1], w2 = dinv[s2], w3 = dinv[s3];
            float p0 = bf2f(h[(long)s0 * 64 + lane]), p1 = bf2f(h[(long)s1 * 64 + lane]);
            float p2 = bf2f(h[(long)s2 * 64 + lane]), p3 = bf2f(h[(long)s3 * 64 + lane]);
            acc = fmaf(p0, w0, acc); acc = fmaf(p1, w1, acc);
            acc = fmaf(p2, w2, acc); acc = fmaf(p3, w3, acc);
        }
        for (; j < j1; ++j) {
            int s = esrc[j];
            acc = fmaf(bf2f(h[(long)s * 64 + lane]), dinv[s], acc);
        }
        As[(wid * 4 + t) * LDT + lane] = f2bf_rtn(acc * wd);
    }
    __syncthreads();

    // MFMA: wave wid -> (r=wid>>2, c=wid&3), K=64
    int r = wid >> 2, c = wid & 3;
    int l15 = lane & 15, l4 = lane >> 4;
    f32x4 acc4 = {};
    #pragma unroll
    for (int ks = 0; ks < 2; ++ks) {
        int koff = ks * 32 + l4 * 8;
        short8v ah = *(const short8v*)&As[(r * 16 + l15) * LDT + koff];
        short8v bh = *(const short8v*)&Bs[(c * 16 + l15) * LDT + koff];
        acc4 = __builtin_amdgcn_mfma_f32_16x16x32_bf16(ah, bh, acc4, 0, 0, 0);
    }
    int rbase = m0 + r * 16 + l4 * 4;
    int gcol = c * 16 + l15;
    #pragma unroll
    for (int q2 = 0; q2 < 4; ++q2) {
        int grow = rbase + q2;
        if (grow >= NN) continue;
        float v = acc4[q2];
        if (gcol < 32)
            out[(long)grow * 32 + gcol] = v + bmu[gcol];
        else
            out[(long)NN * 32 + (long)grow * 32 + (gcol - 32)] = v + bls[gcol - 32];
    }
}

extern "C" void kernel_launch(void* const* d_in, const int* in_sizes, int n_in,
                              void* d_out, int out_size, void* d_ws, size_t ws_size,
                              hipStream_t stream) {
    const float* x   = (const float*)d_in[0];
    const int*   ei  = (const int*)d_in[1];
    const int*   src = ei;       // edge_index[0]
    const int*   dst = ei + NE;  // edge_index[1]
    const float* W1  = (const float*)d_in[2];
    const float* b1  = (const float*)d_in[3];
    const float* W2  = (const float*)d_in[4];
    const float* b2  = (const float*)d_in[5];
    const float* Wmu = (const float*)d_in[6];
    const float* bmu = (const float*)d_in[7];
    const float* Wls = (const float*)d_in[8];
    const float* bls = (const float*)d_in[9];
    float* out = (float*)d_out;

    // ---- workspace layout ----
    char* p = (char*)d_ws;
    float* dinv   = (float*)p; p += 50048 * 4;
    int* counts   = (int*)p;   p += 50048 * 4;  // counts+cursor zeroed together in prep
    int* cursor   = (int*)p;   p += 50048 * 4;
    int* rowstart = (int*)p;   p += 50056 * 4;
    int* bsum     = (int*)p;   p += 256 * 4;
    int* esrc     = (int*)p;   p += 400000 * 4;
    unsigned* xp          = (unsigned*)p;       p += 50000L * 64 * 4;   // packed bf16 x
    unsigned short* xa_hi = (unsigned short*)p; p += 50000L * 128 * 2;  // later h2_hi
    unsigned short* g2b   = (unsigned short*)p; p += 50000L * 64 * 2;
    unsigned short* w1t_hi = (unsigned short*)p; p += 320 * 128 * 2;
    unsigned short* w2t_hi = (unsigned short*)p; p += 64 * 320 * 2;
    unsigned short* wct_hi = (unsigned short*)p; p += 64 * 64 * 2;
    unsigned short* h2_hi = xa_hi;  // xa dead after gemm12

    const int TB = 256;
    const int NB_NODES = (NN + TB - 1) / TB;     // 196
    const int NB_AGG = (NN * 64 + TB - 1) / TB;  // 12500 (wave per node)

    // ---- prep + CSR build ----
    prep_kernel<<<13147, TB, 0, stream>>>(x, W1, W2, Wmu, Wls, xp, counts,
                                          w1t_hi, w2t_hi, wct_hi);
    hist_kernel<<<1024, TB, 0, stream>>>(dst, counts);
    dinv_scan1_kernel<<<NB_NODES, TB, 0, stream>>>(counts, dinv, rowstart, bsum);
    scan23_kernel<<<NB_NODES, TB, 0, stream>>>(rowstart, bsum);
    scatter_kernel<<<1024, TB, 0, stream>>>(src, dst, rowstart, cursor, esrc);

    // ---- layer 1 agg: xa = agg(x) -> bf16 hi ----
    agg109_packed_kernel<<<NB_AGG, TB, 0, stream>>>(rowstart, esrc, dinv, xp,
                                                    (unsigned*)xa_hi);

    // ---- FUSED GEMM1+GEMM2: h1 in LDS; g2b = (relu(xa@W1+b1)@W2)*dinv ----
    gemm12_kernel<<<782, 256, 0, stream>>>(xa_hi, w1t_hi, w2t_hi, b1, dinv, g2b);

    // ---- layer 2 agg: h2 = relu(agg(g2b) + b2) -> bf16 hi ----
    agg64_relu_bf16_kernel<<<NB_AGG, TB, 0, stream>>>(rowstart, esrc, dinv, g2b, b2, h2_hi);

    // ---- layers 3+4 FUSED: aggregate h2 + 64x64x64 GEMM -> out ----
    agg_gemm3_kernel<<<782, 1024, 0, stream>>>(rowstart, esrc, dinv, h2_hi, wct_hi,
                                               bmu, bls, out);
}